// Round 1
// baseline (1270.085 us; speedup 1.0000x reference)
//
#include <hip/hip_runtime.h>
#include <stdint.h>

// Problem constants
#define Bn   2
#define Sn   4096
#define NQn  576
#define Hn   32
#define HDn  128
#define HIDn 4096

typedef unsigned short bfu;  // raw bf16 bits
typedef short short8 __attribute__((ext_vector_type(8)));
typedef float f32x4 __attribute__((ext_vector_type(4)));

__device__ __forceinline__ bfu f2b(float f) {
  uint32_t x = __builtin_bit_cast(uint32_t, f);
  return (bfu)((x + 0x7fffu + ((x >> 16) & 1u)) >> 16);  // RNE
}

__device__ __forceinline__ void gload16(const void* g, void* l) {
  // async global->LDS, 16B per lane; LDS dest = wave-uniform base + lane*16
  __builtin_amdgcn_global_load_lds(
      (const __attribute__((address_space(1))) uint32_t*)g,
      (__attribute__((address_space(3))) uint32_t*)l, 16, 0, 0);
}

// ---------------- cast f32 -> bf16 (vectorized: 2x float4 in, 16B out) ---------
__global__ void cast_f32_bf16(const float* __restrict__ in, bfu* __restrict__ out,
                              int n8) {
  int i = blockIdx.x * 256 + threadIdx.x;
  if (i >= n8) return;
  const float4* in4 = (const float4*)in;
  float4 a = in4[2 * i], c = in4[2 * i + 1];
  short8 v;
  v[0] = (short)f2b(a.x); v[1] = (short)f2b(a.y);
  v[2] = (short)f2b(a.z); v[3] = (short)f2b(a.w);
  v[4] = (short)f2b(c.x); v[5] = (short)f2b(c.y);
  v[6] = (short)f2b(c.z); v[7] = (short)f2b(c.w);
  ((short8*)out)[i] = v;
}

// ---------------- GEMM: C[M][N] = A[M][K] @ Bm[N][K]^T  (m97-style 128^2) ------
// 256 thr = 4 waves (2x2), each wave 64x64 = 4x4 MFMA tiles, BK=32.
template <int WRITE_BF16>
__global__ __launch_bounds__(256, 2)
void gemm_bt(const bfu* __restrict__ A, const bfu* __restrict__ Bm,
             void* __restrict__ Cout, int M, int N, int K) {
  __shared__ bfu As[128 * 32];
  __shared__ bfu Bs[128 * 32];
  const int tid = threadIdx.x;
  const int wave = tid >> 6, lane = tid & 63;
  const int lr = lane & 15, kq = lane >> 4;
  const int wm = wave >> 1, wn = wave & 1;
  const long m0 = (long)blockIdx.y * 128, n0 = (long)blockIdx.x * 128;

  f32x4 acc[4][4] = {};

  for (int kk = 0; kk < K; kk += 32) {
#pragma unroll
    for (int i = 0; i < 2; ++i) {
      int tt = i * 256 + tid;
      long row = tt >> 2;          // [0,128)
      int col = (tt & 3) * 8;      // {0,8,16,24}
      gload16(A + (m0 + row) * K + kk + col, &As[(i * 256 + wave * 64) * 8]);
      gload16(Bm + (n0 + row) * K + kk + col, &Bs[(i * 256 + wave * 64) * 8]);
    }
    __syncthreads();
    short8 a[4], b[4];
#pragma unroll
    for (int mt = 0; mt < 4; ++mt)
      a[mt] = *(const short8*)&As[(wm * 64 + mt * 16 + lr) * 32 + kq * 8];
#pragma unroll
    for (int nt = 0; nt < 4; ++nt)
      b[nt] = *(const short8*)&Bs[(wn * 64 + nt * 16 + lr) * 32 + kq * 8];
#pragma unroll
    for (int mt = 0; mt < 4; ++mt)
#pragma unroll
      for (int nt = 0; nt < 4; ++nt)
        acc[mt][nt] = __builtin_amdgcn_mfma_f32_16x16x32_bf16(
            a[mt], b[nt], acc[mt][nt], 0, 0, 0);
    __syncthreads();
  }
  // epilogue: C/D layout col=lane&15, row=(lane>>4)*4+reg  [m89-verified]
#pragma unroll
  for (int mt = 0; mt < 4; ++mt)
#pragma unroll
    for (int nt = 0; nt < 4; ++nt)
#pragma unroll
      for (int r = 0; r < 4; ++r) {
        long row = m0 + wm * 64 + mt * 16 + kq * 4 + r;
        long col = n0 + wn * 64 + nt * 16 + lr;
        float v = acc[mt][nt][r];
        if (WRITE_BF16)
          ((bfu*)Cout)[row * N + col] = f2b(v);
        else
          ((float*)Cout)[row * N + col] = v;
      }
}

// ---------------- V transpose: Vb[B*NQ][HID] -> Vt[B*H][HD][NQ] ----------------
__global__ void transpose_v(const bfu* __restrict__ Vb, bfu* __restrict__ Vt) {
  __shared__ bfu t[32][33];
  const int bh = blockIdx.z;            // b*H + h
  const int tq = blockIdx.x;            // nq tile [0,18)
  const int td = blockIdx.y;            // d tile  [0,4)
  const int b = bh >> 5, h = bh & 31;
  const int tx = threadIdx.x & 31, ty = threadIdx.x >> 5;  // ty in [0,8)
  const bfu* src = Vb + ((long)(b * NQn + tq * 32)) * HIDn + h * HDn + td * 32;
#pragma unroll
  for (int i = 0; i < 32; i += 8) t[ty + i][tx] = src[(long)(ty + i) * HIDn + tx];
  __syncthreads();
  bfu* dst = Vt + ((long)bh * HDn + td * 32) * NQn + tq * 32;
#pragma unroll
  for (int i = 0; i < 32; i += 8) dst[(long)(ty + i) * NQn + tx] = t[tx][ty + i];
}

// ---------------- fused attention: QK^T -> mask -> softmax -> PV ---------------
// block = (qt, b, h): 32 q-rows; 4 waves each own 144 key cols for QK^T,
// then 32 output dims for PV. Softmax normalization deferred to epilogue.
__global__ __launch_bounds__(256, 2)
void attn_kernel(const bfu* __restrict__ Qb, const bfu* __restrict__ Kb,
                 const bfu* __restrict__ Vt, const float* __restrict__ mask,
                 bfu* __restrict__ AO) {
  const int bid = blockIdx.x;
  const int h = bid & (Hn - 1);
  const int b = (bid >> 5) & (Bn - 1);
  const int qt = bid >> 6;  // [0,128)
  const int tid = threadIdx.x;
  const int wave = tid >> 6, lane = tid & 63;
  const int lr = lane & 15, kq = lane >> 4;
  const float scale = 0.08838834764831845f;  // 1/sqrt(128)

  __shared__ float red[4][32];
  __shared__ bfu P[32][584];  // +8 pad: row stride 1168B == 4-bank shift -> no conflict

  // Q fragments straight from global (one-time, L2-served)
  const bfu* Qbase = Qb + ((long)(b * Sn + qt * 32)) * HIDn + h * HDn;
  short8 qf[2][4];
#pragma unroll
  for (int mt = 0; mt < 2; ++mt)
#pragma unroll
    for (int ks = 0; ks < 4; ++ks)
      qf[mt][ks] =
          *(const short8*)&Qbase[(long)(mt * 16 + lr) * HIDn + ks * 32 + kq * 8];

  // QK^T: scores for cols [wave*144, +144) = 9 N-tiles, K=128 in 4 steps
  f32x4 sc[2][9] = {};
  const bfu* Kbase = Kb + ((long)(b * NQn)) * HIDn + h * HDn;
  const int nc0 = wave * 144;
#pragma unroll
  for (int nt = 0; nt < 9; ++nt) {
#pragma unroll
    for (int ks = 0; ks < 4; ++ks) {
      short8 kf = *(const short8*)&Kbase[(long)(nc0 + nt * 16 + lr) * HIDn +
                                         ks * 32 + kq * 8];
      sc[0][nt] = __builtin_amdgcn_mfma_f32_16x16x32_bf16(qf[0][ks], kf, sc[0][nt], 0, 0, 0);
      sc[1][nt] = __builtin_amdgcn_mfma_f32_16x16x32_bf16(qf[1][ks], kf, sc[1][nt], 0, 0, 0);
    }
  }

  // scale + mask; per-lane row max (rows: mt*16 + kq*4 + r, cols: nc0+nt*16+lr)
  const float* mbase = mask + ((long)(b * Sn + qt * 32)) * NQn;
  float rmax[2][4];
#pragma unroll
  for (int mt = 0; mt < 2; ++mt)
#pragma unroll
    for (int r = 0; r < 4; ++r) rmax[mt][r] = -1e30f;
#pragma unroll
  for (int mt = 0; mt < 2; ++mt)
#pragma unroll
    for (int nt = 0; nt < 9; ++nt)
#pragma unroll
      for (int r = 0; r < 4; ++r) {
        float mv = mbase[(long)(mt * 16 + kq * 4 + r) * NQn + nc0 + nt * 16 + lr];
        float sv = sc[mt][nt][r] * scale + mv;
        sc[mt][nt][r] = sv;
        rmax[mt][r] = fmaxf(rmax[mt][r], sv);
      }
  // reduce across the 16 lanes holding one row (xor 1,2,4,8 stays in 16-group)
#pragma unroll
  for (int d = 1; d < 16; d <<= 1)
#pragma unroll
    for (int mt = 0; mt < 2; ++mt)
#pragma unroll
      for (int r = 0; r < 4; ++r)
        rmax[mt][r] = fmaxf(rmax[mt][r], __shfl_xor(rmax[mt][r], d, 64));
  if (lr == 0)
#pragma unroll
    for (int mt = 0; mt < 2; ++mt)
#pragma unroll
      for (int r = 0; r < 4; ++r) red[wave][mt * 16 + kq * 4 + r] = rmax[mt][r];
  __syncthreads();
  float gmax[2][4];
#pragma unroll
  for (int mt = 0; mt < 2; ++mt)
#pragma unroll
    for (int r = 0; r < 4; ++r) {
      int row = mt * 16 + kq * 4 + r;
      gmax[mt][r] = fmaxf(fmaxf(red[0][row], red[1][row]),
                          fmaxf(red[2][row], red[3][row]));
    }
  __syncthreads();  // everyone done reading red before sum pass reuses it

  // exp + row sums
  float rsum[2][4] = {};
#pragma unroll
  for (int mt = 0; mt < 2; ++mt)
#pragma unroll
    for (int nt = 0; nt < 9; ++nt)
#pragma unroll
      for (int r = 0; r < 4; ++r) {
        float p = __expf(sc[mt][nt][r] - gmax[mt][r]);
        sc[mt][nt][r] = p;
        rsum[mt][r] += p;
      }
#pragma unroll
  for (int d = 1; d < 16; d <<= 1)
#pragma unroll
    for (int mt = 0; mt < 2; ++mt)
#pragma unroll
      for (int r = 0; r < 4; ++r) rsum[mt][r] += __shfl_xor(rsum[mt][r], d, 64);
  if (lr == 0)
#pragma unroll
    for (int mt = 0; mt < 2; ++mt)
#pragma unroll
      for (int r = 0; r < 4; ++r) red[wave][mt * 16 + kq * 4 + r] = rsum[mt][r];

  // stage unnormalized P (bf16) in LDS
#pragma unroll
  for (int mt = 0; mt < 2; ++mt)
#pragma unroll
    for (int nt = 0; nt < 9; ++nt)
#pragma unroll
      for (int r = 0; r < 4; ++r)
        P[mt * 16 + kq * 4 + r][nc0 + nt * 16 + lr] = f2b(sc[mt][nt][r]);
  __syncthreads();

  float inv[2][4];
#pragma unroll
  for (int mt = 0; mt < 2; ++mt)
#pragma unroll
    for (int r = 0; r < 4; ++r) {
      int row = mt * 16 + kq * 4 + r;
      inv[mt][r] = 1.0f / (red[0][row] + red[1][row] + red[2][row] + red[3][row]);
    }

  // PV: wave owns d-slice [wave*32, +32); K-dim = 576 in 18 steps
  f32x4 o[2][2] = {};
  const bfu* Vbase = Vt + ((long)(b * Hn + h)) * HDn * NQn + (long)wave * 32 * NQn;
  for (int ks = 0; ks < 18; ++ks) {
    short8 pa[2], vb[2];
#pragma unroll
    for (int mt = 0; mt < 2; ++mt)
      pa[mt] = *(const short8*)&P[mt * 16 + lr][ks * 32 + kq * 8];
#pragma unroll
    for (int nt = 0; nt < 2; ++nt)
      vb[nt] = *(const short8*)&Vbase[(long)(nt * 16 + lr) * NQn + ks * 32 + kq * 8];
#pragma unroll
    for (int mt = 0; mt < 2; ++mt)
#pragma unroll
      for (int nt = 0; nt < 2; ++nt)
        o[mt][nt] = __builtin_amdgcn_mfma_f32_16x16x32_bf16(pa[mt], vb[nt], o[mt][nt], 0, 0, 0);
  }
  bfu* Obase = AO + ((long)(b * Sn + qt * 32)) * HIDn + h * HDn + wave * 32;
#pragma unroll
  for (int mt = 0; mt < 2; ++mt)
#pragma unroll
    for (int nt = 0; nt < 2; ++nt)
#pragma unroll
      for (int r = 0; r < 4; ++r)
        Obase[(long)(mt * 16 + kq * 4 + r) * HIDn + nt * 16 + lr] =
            f2b(o[mt][nt][r] * inv[mt][r]);
}

// ------------------------------- launcher --------------------------------------
extern "C" void kernel_launch(void* const* d_in, const int* in_sizes, int n_in,
                              void* d_out, int out_size, void* d_ws, size_t ws_size,
                              hipStream_t stream) {
  const float* hs = (const float*)d_in[0];
  const float* bp = (const float*)d_in[1];
  const float* mask = (const float*)d_in[2];
  const float* Wq = (const float*)d_in[3];
  const float* Wk = (const float*)d_in[4];
  const float* Wv = (const float*)d_in[5];
  const float* Wo = (const float*)d_in[6];
  float* out = (float*)d_out;

  const long M1 = (long)Bn * Sn;   // 8192
  const long M2 = (long)Bn * NQn;  // 1152
  char* ws = (char*)d_ws;
  // workspace layout (bytes); hb slot reused as attn-out, w1 slot as Wq then Wo
  bfu* hb = (bfu*)(ws + 0);                  // 67,108,864  (also AO)
  bfu* bb = (bfu*)(ws + 67108864);           //  9,437,184
  bfu* w1 = (bfu*)(ws + 76546048);           // 33,554,432  (Wq, later Wo)
  bfu* wkb = (bfu*)(ws + 110100480);         // 33,554,432
  bfu* wvb = (bfu*)(ws + 143654912);         // 33,554,432
  bfu* Qb = (bfu*)(ws + 177209344);          // 67,108,864
  bfu* Kb = (bfu*)(ws + 244318208);          //  9,437,184
  bfu* Vb = (bfu*)(ws + 253755392);          //  9,437,184
  bfu* Vt = (bfu*)(ws + 263192576);          //  9,437,184  -> total 272,629,760

  auto cast = [&](const float* src, bfu* dst, long n) {
    int n8 = (int)(n / 8);
    cast_f32_bf16<<<dim3((n8 + 255) / 256), dim3(256), 0, stream>>>(src, dst, n8);
  };
  cast(hs, hb, M1 * HIDn);
  cast(bp, bb, M2 * HIDn);
  cast(Wq, w1, (long)HIDn * HIDn);
  cast(Wk, wkb, (long)HIDn * HIDn);
  cast(Wv, wvb, (long)HIDn * HIDn);

  gemm_bt<1><<<dim3(HIDn / 128, M1 / 128), dim3(256), 0, stream>>>(
      hb, w1, Qb, (int)M1, HIDn, HIDn);
  gemm_bt<1><<<dim3(HIDn / 128, M2 / 128), dim3(256), 0, stream>>>(
      bb, wkb, Kb, (int)M2, HIDn, HIDn);
  gemm_bt<1><<<dim3(HIDn / 128, M2 / 128), dim3(256), 0, stream>>>(
      bb, wvb, Vb, (int)M2, HIDn, HIDn);

  cast(Wo, w1, (long)HIDn * HIDn);  // w1 slot free after Q-proj
  transpose_v<<<dim3(NQn / 32, HDn / 32, Bn * Hn), dim3(256), 0, stream>>>(Vb, Vt);

  attn_kernel<<<dim3((Sn / 32) * Bn * Hn), dim3(256), 0, stream>>>(
      Qb, Kb, Vt, mask, hb /*AO aliases hb*/);

  gemm_bt<0><<<dim3(HIDn / 128, M1 / 128), dim3(256), 0, stream>>>(
      hb, w1, out, (int)M1, HIDn, HIDn);
}